// Round 4
// baseline (119.380 us; speedup 1.0000x reference)
//
#include <hip/hip_runtime.h>
#include <hip/hip_bf16.h>

// R16: MEASUREMENT ROUND == R15 byte-identical (kernel 44.5-46.4us, dur
// 113.9) + FOUR DUMMY GRID BARRIERS appended after bar4 (regions 4..7) ==
// Purpose: R13-R15 post-mortems show my latency model (~15us) underestimates
// the measured 44us kernel by 3x, and the split between barrier cost and
// phase-body cost is unknown. The dummies run when all blocks are already
// synced (zero skew), so Delta_kernel/4 = pure cost of one store-based grid
// barrier. Pre-committed decision rules:
//   B<1.5us  -> barriers minor; attack phase latency chains (B/E/C/F).
//   B=1.5-3  -> mixed; phases first.
//   B>3us    -> sync dominates; XCD-hierarchical barrier / 2-barrier restruct.
// Everything else unchanged (sleep(8) kept for clean interpretation).
// Structure (validated R1-R12): looper == sigmoid(3.0) exactly -> exactly two
// long_conv applications; lc_* inputs unused. Phases:
//   A: key1[3][1024] = sigmoid(sampled stride-2 conv of 2x-1)  [distributed]
//   bar1
//   B: logit1[100] = keys @ key1, one block per row (keys row in regs)
//   bar2
//   C: softmax -> kern1 (LDS) -> w_eff (LDS)            [REPLICATED, all blocks]
//   D: key2 via w_eff (composite conv(convT(.,kern1)))          [distributed]
//   bar3
//   E: logit2[100]
//   bar4  (+ 4 dummy barriers, measurement only)
//   F: softmax -> kern2 (LDS) -> composite stride-4 13x13 convT weights
//   G: out = sigmoid(composite convT), taps in LDS
// Ledger (measured): agent acquire/release fences forbidden (R4); cross-block
// data sc1 relaxed-agent only; sc1 store->load visibility validated (R8); no
// dynamic-indexed register arrays (R7 spill); no rolled global-load loops
// (R11); entry prefetch of all static loads (R12 win); keys row-wise only
// (R13); no long-lived prefetch regs across barriers (R14); G tail negligible
// (R15 neutral). Deadlock safety: 128 blocks x 256 thr, launch_bounds(256,1),
// ~35KB LDS -> co-resident. Barrier state (8 x 1KB) zeroed each call.

#define GRID 128

#define LD1(p)     __hip_atomic_load((p), __ATOMIC_RELAXED, __HIP_MEMORY_SCOPE_AGENT)
#define ST1(p, v)  __hip_atomic_store((p), (v), __ATOMIC_RELAXED, __HIP_MEMORY_SCOPE_AGENT)

__device__ __forceinline__ float sigmoidf_(float z) {
    return 1.0f / (1.0f + expf(-z));
}

// base: 256 words (1KB). arrival[0..127]; release flag at word 160.
// No atomics anywhere: stores + loads only. (R12-validated)
__device__ __forceinline__ void gbar(unsigned* base, int blk, int t) {
    asm volatile("s_waitcnt vmcnt(0)" ::: "memory");   // data sc1 stores visible
    __syncthreads();
    if (t == 0) ST1(base + blk, 1u);                   // arrival store, own word
    if (blk == 0) {
        if (t < 128) {                                 // 2 waves poll 128 words
            while (LD1(base + t) == 0u)
                __builtin_amdgcn_s_sleep(8);
        }
        __syncthreads();
        if (t == 0) ST1(base + 160, 1u);               // release flag, own line
    } else {
        if (t == 0) {
            while (LD1(base + 160) == 0u)
                __builtin_amdgcn_s_sleep(8);
        }
        __syncthreads();
    }
    asm volatile("" ::: "memory");
    __syncthreads();
}

// entry tap loads for one key stage (2 samples/wave; sample = blk*4+wv+rep*512)
__device__ __forceinline__ void key_prefetch(const float* __restrict__ in,
                                             int mul, int dbl, int blk,
                                             int lane, int wv,
                                             float xa[2], float xb[2]) {
#pragma unroll
    for (int rep = 0; rep < 2; ++rep) {
        int s = blk * 4 + wv + rep * 512;
        int ii = s >> 5, jj = s & 31;
        int qy = (ii * mul) >> 5, qx = (jj * mul) >> 5;
        int by = dbl ? 2 * qy : qy - 1;
        int bx = dbl ? 2 * qx : qx - 1;
        {
            int l = lane;                    // < 64 < 75: always a valid tap
            int ci = l / 25, rm = l % 25, r = rm / 5, cc = rm % 5;
            int y = by + r, x = bx + cc;
            xa[rep] = ((unsigned)y < 1024u && (unsigned)x < 1024u)
                      ? 2.0f * in[ci * 1048576 + y * 1024 + x] - 1.0f : 0.f;
        }
        xb[rep] = 0.f;
        if (lane < 11) {
            int l = lane + 64;
            int ci = l / 25, rm = l % 25, r = rm / 5, cc = rm % 5;
            int y = by + r, x = bx + cc;
            xb[rep] = ((unsigned)y < 1024u && (unsigned)x < 1024u)
                      ? 2.0f * in[ci * 1048576 + y * 1024 + x] - 1.0f : 0.f;
        }
    }
}

// key values from prefetched taps -> key[3][1024] via sc1 stores
__device__ __forceinline__ void key_phase(const float* __restrict__ sw,
                                          const float* __restrict__ sb,
                                          const float xa[2], const float xb[2],
                                          float* __restrict__ keyout,
                                          int blk, int lane, int wv) {
#pragma unroll
    for (int rep = 0; rep < 2; ++rep) {
        int s = blk * 4 + wv + rep * 512;
        float p0 = xa[rep] * sw[lane];
        float p1 = xa[rep] * sw[75 + lane];
        float p2 = xa[rep] * sw[150 + lane];
        if (lane < 11) {
            p0 += xb[rep] * sw[64 + lane];
            p1 += xb[rep] * sw[139 + lane];
            p2 += xb[rep] * sw[214 + lane];
        }
#pragma unroll
        for (int off = 32; off > 0; off >>= 1) {
            p0 += __shfl_xor(p0, off, 64);
            p1 += __shfl_xor(p1, off, 64);
            p2 += __shfl_xor(p2, off, 64);
        }
        if (lane == 0) {
            ST1(keyout + s,        sigmoidf_(p0 + sb[0]));
            ST1(keyout + 1024 + s, sigmoidf_(p1 + sb[1]));
            ST1(keyout + 2048 + s, sigmoidf_(p2 + sb[2]));
        }
    }
}

// logits with pre-loaded keys row (kvr[12], loaded at entry)
__device__ __forceinline__ void logits_phase(const float kvr[12],
                                             const float* __restrict__ keyvec,
                                             float* __restrict__ logit,
                                             int n, int t, int lane, int wv,
                                             float* __restrict__ sred) {
    float s = 0.f;
#pragma unroll
    for (int m = 0; m < 12; ++m) s += kvr[m] * LD1(keyvec + m * 256 + t);
#pragma unroll
    for (int off = 32; off > 0; off >>= 1) s += __shfl_xor(s, off, 64);
    if (lane == 0) sred[wv] = s;
    __syncthreads();
    if (t == 0) ST1(logit + n, sred[0] + sred[1] + sred[2] + sred[3]);
}

// softmax(logit[100]) -> satt (uncached logit reads; runs in every block)
__device__ __forceinline__ void softmax_phase(const float* __restrict__ logit,
                                              float* __restrict__ satt,
                                              int lane, int wv) {
    if (wv == 0) {
        float v1 = LD1(logit + lane);
        float v2 = (lane + 64 < 100) ? LD1(logit + lane + 64) : -3.4e38f;
        float mx = fmaxf(v1, v2);
#pragma unroll
        for (int off = 32; off > 0; off >>= 1) mx = fmaxf(mx, __shfl_xor(mx, off, 64));
        float e1 = expf(v1 - mx);
        float e2 = (lane + 64 < 100) ? expf(v2 - mx) : 0.f;
        float s = e1 + e2;
#pragma unroll
        for (int off = 32; off > 0; off >>= 1) s += __shfl_xor(s, off, 64);
        float inv = 1.0f / s;
        satt[lane] = e1 * inv;
        if (lane + 64 < 100) satt[lane + 64] = e2 * inv;
    }
    __syncthreads();
}

__global__ __launch_bounds__(256, 1) void k_fused(
    const float* __restrict__ in, const float* __restrict__ cw,
    const float* __restrict__ cb, const float* __restrict__ keys,
    const float* __restrict__ vals, float* __restrict__ out,
    float* __restrict__ ws, unsigned* __restrict__ ctr)
{
    __shared__ float smem[8768];
    float* sk1  = smem;          // 225  kern1 (persists C->F)
    float* sk2  = smem + 232;    // 225  kern2
    float* satt = smem + 464;    // 100  softmax
    float* sred = smem + 576;    // 4    cross-wave reduce
    float* sw   = smem + 592;    // 225  conv weights, then w_eff
    float* sb   = smem + 824;    // 3    bias
    float* sW   = smem + 832;    // 1521 composite W [(ci*3+o)*169 + e*13+f]
    float* sWy  = smem + 2356;   // 117
    float* sWx  = smem + 2480;   // 117
    float* sWxy = smem + 2600;   // 9
    float* sgx  = smem + 2624;   // 6144 G taps [((ch*4+k)*4+l)*128 + j]

    float* key1   = ws;          // 3072
    float* logit1 = ws + 3072;   // 100
    float* key2   = ws + 3200;   // 3072
    float* logit2 = ws + 6400;   // 100

    const int t = threadIdx.x, lane = t & 63, wv = t >> 6;
    const int blk = blockIdx.x;

    // ---- entry prefetch: both stages' taps + this block's keys row ----
    float xa1[2], xb1[2], xa2[2], xb2[2];
    key_prefetch(in, 510, 1, blk, lane, wv, xa1, xb1);
    key_prefetch(in, 1022, 0, blk, lane, wv, xa2, xb2);
    float kvr[12];
    if (blk < 100) {
        const float* kr = keys + blk * 3072;
#pragma unroll
        for (int m = 0; m < 12; ++m) kvr[m] = kr[m * 256 + t];
    } else {
#pragma unroll
        for (int m = 0; m < 12; ++m) kvr[m] = 0.f;
    }

    // ---- entry: stage G taps into LDS (registers die here; R14 lesson) ----
    const int j = t & 127, h = t >> 7;
    const int R = (blk * 4093) >> 7;
    const int C = (j * 4093) >> 7;
    const int ybase = (R + 6) >> 2, r0 = (R + 6) & 3, nk = (r0 == 0) ? 4 : 3;
    const int xbase = (C + 6) >> 2, f0 = (C + 6) & 3, nl = (f0 == 0) ? 4 : 3;
#pragma unroll
    for (int k = 0; k < 4; ++k) {
        int iy = ybase - k;
#pragma unroll
        for (int lh = 0; lh < 2; ++lh) {
            int l = h * 2 + lh;
            int ix = xbase - l;
            bool ok = ((unsigned)iy < 1024u) && ((unsigned)ix < 1024u)
                      && (k < nk) && (l < nl);
            int off = iy * 1024 + ix;
            float v0 = ok ? 2.0f * in[off] - 1.0f : 0.f;
            float v1 = ok ? 2.0f * in[1048576 + off] - 1.0f : 0.f;
            float v2 = ok ? 2.0f * in[2097152 + off] - 1.0f : 0.f;
            int si = (k * 4 + l) * 128 + j;
            sgx[si]        = v0;
            sgx[2048 + si] = v1;
            sgx[4096 + si] = v2;
        }
    }

    if (t < 225) sw[t] = cw[t];
    if (t < 3)   sb[t] = cb[t];
    __syncthreads();

    // ---- A: key1 (distributed) ----
    key_phase(sw, sb, xa1, xb1, key1, blk, lane, wv);
    gbar(ctr + 0 * 256, blk, t);

    // ---- B: logit1 (blocks 0..99) ----
    if (blk < 100) logits_phase(kvr, key1, logit1, blk, t, lane, wv, sred);
    gbar(ctr + 1 * 256, blk, t);

    // ---- C (replicated): softmax + kern1 -> LDS, w_eff -> LDS ----
    softmax_phase(logit1, satt, lane, wv);
    if (t < 225) {
        float s = 0.f;
#pragma unroll
        for (int n = 0; n < 100; ++n) s += vals[n * 225 + t] * satt[n];
        sk1[t] = s;
    }
    __syncthreads();
    if (t < 225) {   // w_eff[co][ci][a][bb] = conv(convT(.,kern1)) composite
        int co = t / 75, rem = t % 75, ci = rem / 25, a = (rem % 25) / 5, bb = rem % 5;
        float s = 0.f;
#pragma unroll
        for (int c = 0; c < 5; ++c) {
            int u = c + 2 * a - 4;
            if ((unsigned)u >= 5u) continue;
#pragma unroll
            for (int d = 0; d < 5; ++d) {
                int v = d + 2 * bb - 4;
                if ((unsigned)v >= 5u) continue;
#pragma unroll
                for (int cm = 0; cm < 3; ++cm)
                    s += sk1[ci * 75 + cm * 25 + c * 5 + d] * cw[co * 75 + cm * 25 + u * 5 + v];
            }
        }
        sw[t] = s;    // nobody reads old sw in this phase
    }
    __syncthreads();

    // ---- D: key2 via w_eff (distributed) ----
    key_phase(sw, sb, xa2, xb2, key2, blk, lane, wv);
    gbar(ctr + 2 * 256, blk, t);

    // ---- E: logit2 (blocks 0..99) ----
    if (blk < 100) logits_phase(kvr, key2, logit2, blk, t, lane, wv, sred);
    gbar(ctr + 3 * 256, blk, t);

    // ==== MEASUREMENT: 4 dummy barriers, all blocks synced, zero skew ====
    gbar(ctr + 4 * 256, blk, t);
    gbar(ctr + 5 * 256, blk, t);
    gbar(ctr + 6 * 256, blk, t);
    gbar(ctr + 7 * 256, blk, t);

    // ---- F (replicated): softmax + kern2 -> LDS, composite tables -> LDS ----
    softmax_phase(logit2, satt, lane, wv);
    if (t < 225) {
        float s = 0.f;
#pragma unroll
        for (int n = 0; n < 100; ++n) s += vals[n * 225 + t] * satt[n];
        sk2[t] = s;
    }
    __syncthreads();
    for (int idx = t; idx < 1521; idx += 256) {   // W
        int ci = idx / 507, rem = idx % 507, o = rem / 169;
        int ef = rem % 169, e = ef / 13, f = ef % 13;
        float s = 0.f;
#pragma unroll
        for (int c = 0; c < 5; ++c) {
            int a = e - 2 * c;
            if ((unsigned)a >= 5u) continue;
#pragma unroll
            for (int d = 0; d < 5; ++d) {
                int b2 = f - 2 * d;
                if ((unsigned)b2 >= 5u) continue;
#pragma unroll
                for (int cm = 0; cm < 3; ++cm)
                    s += sk1[ci * 75 + cm * 25 + c * 5 + d] * sk2[cm * 75 + o * 25 + a * 5 + b2];
            }
        }
        sW[idx] = s;
    }
    if (t < 117) {   // Wy: phantom out1-row (c=1 -> oy1=-1), a=4
        int ci = t / 39, o = (t % 39) / 13, f = t % 13;
        float s = 0.f;
#pragma unroll
        for (int d = 0; d < 5; ++d) {
            int b2 = f - 2 * d;
            if ((unsigned)b2 >= 5u) continue;
#pragma unroll
            for (int cm = 0; cm < 3; ++cm)
                s += sk1[ci * 75 + cm * 25 + 5 + d] * sk2[cm * 75 + o * 25 + 20 + b2];
        }
        sWy[(ci * 3 + o) * 13 + f] = s;
    }
    if (t >= 128 && t < 245) {   // Wx: phantom out1-col (d=1 -> ox1=-1), b=4
        int q = t - 128;
        int ci = q / 39, o = (q % 39) / 13, e = q % 13;
        float s = 0.f;
#pragma unroll
        for (int c = 0; c < 5; ++c) {
            int a = e - 2 * c;
            if ((unsigned)a >= 5u) continue;
#pragma unroll
            for (int cm = 0; cm < 3; ++cm)
                s += sk1[ci * 75 + cm * 25 + c * 5 + 1] * sk2[cm * 75 + o * 25 + a * 5 + 4];
        }
        sWx[(ci * 3 + o) * 13 + e] = s;
    }
    if (t >= 246 && t < 255) {   // Wxy overlap
        int q = t - 246;
        int ci = q / 3, o = q % 3;
        float s = 0.f;
#pragma unroll
        for (int cm = 0; cm < 3; ++cm)
            s += sk1[ci * 75 + cm * 25 + 5 + 1] * sk2[cm * 75 + o * 25 + 20 + 4];
        sWxy[ci * 3 + o] = s;
    }
    __syncthreads();

    // ---- G: final sampled composite convT + sigmoid (taps + tables in LDS) ----
    if (t < 128) {
        float a0 = 0.f, a1 = 0.f, a2 = 0.f;
#pragma unroll
        for (int k = 0; k < 4; ++k) {
            if (k < nk) {
                int e = r0 + 4 * k;
#pragma unroll
                for (int l = 0; l < 4; ++l) {
                    if (l < nl) {
                        int f = f0 + 4 * l;
                        int wi = e * 13 + f;
                        int si = (k * 4 + l) * 128 + j;
                        float x0 = sgx[si], x1 = sgx[2048 + si], x2 = sgx[4096 + si];
                        a0 += x0 * sW[wi]       + x1 * sW[507 + wi]  + x2 * sW[1014 + wi];
                        a1 += x0 * sW[169 + wi] + x1 * sW[676 + wi]  + x2 * sW[1183 + wi];
                        a2 += x0 * sW[338 + wi] + x1 * sW[845 + wi]  + x2 * sW[1352 + wi];
                    }
                }
            }
        }
        if (R == 0) {
            for (int l = 0; l < nl; ++l) {
                int ix = xbase - l;
                if ((unsigned)ix >= 1024u) continue;
                int f = f0 + 4 * l;
                float x0 = 2.0f * in[ix] - 1.0f;
                float x1 = 2.0f * in[1048576 + ix] - 1.0f;
                float x2 = 2.0f * in[2097152 + ix] - 1.0f;
                a0 -= x0 * sWy[f]      + x1 * sWy[39 + f] + x2 * sWy[78 + f];
                a1 -= x0 * sWy[13 + f] + x1 * sWy[52 + f] + x2 * sWy[91 + f];
                a2 -= x0 * sWy[26 + f] + x1 * sWy[65 + f] + x2 * sWy[104 + f];
            }
        }
        if (C == 0) {
            for (int k = 0; k < nk; ++k) {
                int iy = ybase - k;
                if ((unsigned)iy >= 1024u) continue;
                int e = r0 + 4 * k;
                int off = iy * 1024;
                float x0 = 2.0f * in[off] - 1.0f;
                float x1 = 2.0f * in[1048576 + off] - 1.0f;
                float x2 = 2.0f * in[2097152 + off] - 1.0f;
                a0 -= x0 * sWx[e]      + x1 * sWx[39 + e] + x2 * sWx[78 + e];
                a1 -= x0 * sWx[13 + e] + x1 * sWx[52 + e] + x2 * sWx[91 + e];
                a2 -= x0 * sWx[26 + e] + x1 * sWx[65 + e] + x2 * sWx[104 + e];
            }
        }
        if (R == 0 && C == 0) {
            float x0 = 2.0f * in[0] - 1.0f;
            float x1 = 2.0f * in[1048576] - 1.0f;
            float x2 = 2.0f * in[2097152] - 1.0f;
            a0 += x0 * sWxy[0] + x1 * sWxy[3] + x2 * sWxy[6];
            a1 += x0 * sWxy[1] + x1 * sWxy[4] + x2 * sWxy[7];
            a2 += x0 * sWxy[2] + x1 * sWxy[5] + x2 * sWxy[8];
        }
        int T = blk * 128 + j;
        out[T]             = sigmoidf_(a0);
        out[16384 + T]     = sigmoidf_(a1);
        out[2 * 16384 + T] = sigmoidf_(a2);
    }
}

extern "C" void kernel_launch(void* const* d_in, const int* in_sizes, int n_in,
                              void* d_out, int out_size, void* d_ws, size_t ws_size,
                              hipStream_t stream) {
    const float* in   = (const float*)d_in[0];   // [3,1024,1024]
    const float* cw   = (const float*)d_in[1];   // [3,3,5,5]
    const float* cb   = (const float*)d_in[2];   // [3]
    const float* keys = (const float*)d_in[3];   // [100,3072]
    const float* vals = (const float*)d_in[4];   // [100,225]
    float* out = (float*)d_out;                  // [3,128,128] fp32

    unsigned* ctr = (unsigned*)d_ws;             // 8 barriers x 1KB (store-based)
    float* wsf = (float*)((char*)d_ws + 8192);   // float scratch region

    hipMemsetAsync(d_ws, 0, 8192, stream);       // zero barrier state (8 regions)
    k_fused<<<GRID, 256, 0, stream>>>(in, cw, cb, keys, vals, out, wsf, ctr);
}

// Round 5
// 111.175 us; speedup vs baseline: 1.0738x; 1.0738x over previous
//
#include <hip/hip_runtime.h>
#include <hip/hip_bf16.h>

// R17: TWO-BARRIER transposed-logit structure (R13) with the R14/R15 spill
// fix (ALL entry prefetches staged through LDS, registers die at entry).
// == Measurement basis ==
// R16 isolated the grid-barrier cost: 4 dummy barriers added +29.3us =>
// B ~= 7.3us/barrier (implementation-resistant: invariant to RMW->store,
// sleep tuning, fan-in per R9-R12). R15's 44.5us = 4 x 7.3 sync + ~15us
// phases. Sync dominates -> reduce barrier COUNT to the structural minimum:
// one gather per stage = 2 barriers.
// == Why R13 (same structure) regressed, and the fix ==
// R13 carried 24 keys-column floats + 24 G-tap floats in registers across
// memory-clobber barriers -> spill to scratch (R14 isolated: VGPR dropped
// 56->52, FETCH/WRITE unchanged, +19-27us). R15 validated the antidote:
// stage through LDS at entry. Here: keys columns -> skc[100x25] (padded,
// conflict-free), G taps -> sgx[6144]; only xa2/xb2 (4 floats) live across
// bar1. No kvr (keys row reads gone entirely).
// Phases:
//   entry: xa/xb taps, keys columns -> skc, G taps -> sgx, cw/cb -> LDS
//   A: block's 8 key1 samples -> skv (LDS) ; partial logits (skc x skv)
//      -> plog1[blk][100]                                   [all blocks]
//   bar1
//   C': reduce 128 partials -> slog -> softmax -> kern1 -> w_eff [REPLICATED]
//   D: key2 samples via w_eff -> skv ; partials -> plog2       [all blocks]
//   bar2
//   F': reduce -> softmax -> kern2 -> composite 13x13 tables W/Wy/Wx/Wxy
//   G: out = sigmoid(composite convT), taps from sgx           [t<128]
// Ledger (measured): agent acquire/release fences forbidden (R4); cross-block
// data sc1 relaxed-agent only (R8); no dynamic-indexed register arrays (R7);
// no rolled global-load loops (R11); entry prefetch of all static loads
// (R12); NO long-lived prefetch regs across barriers - stage via LDS (R14,
// R15); barrier cost ~7.3us each, implementation-resistant (R16) -> minimize
// count. Deadlock safety: 128 blocks x 256 thr, launch_bounds(256,1), ~46KB
// LDS -> co-resident on 256 CUs. Barrier state (2 x 1KB) zeroed each call.

#define GRID 128

#define LD1(p)     __hip_atomic_load((p), __ATOMIC_RELAXED, __HIP_MEMORY_SCOPE_AGENT)
#define ST1(p, v)  __hip_atomic_store((p), (v), __ATOMIC_RELAXED, __HIP_MEMORY_SCOPE_AGENT)

__device__ __forceinline__ float sigmoidf_(float z) {
    return 1.0f / (1.0f + expf(-z));
}

// base: 256 words (1KB). arrival[0..127]; release flag at word 160.
// No atomics anywhere: stores + loads only. (R12-validated)
__device__ __forceinline__ void gbar(unsigned* base, int blk, int t) {
    asm volatile("s_waitcnt vmcnt(0)" ::: "memory");   // data sc1 stores visible
    __syncthreads();
    if (t == 0) ST1(base + blk, 1u);                   // arrival store, own word
    if (blk == 0) {
        if (t < 128) {                                 // 2 waves poll 128 words
            while (LD1(base + t) == 0u)
                __builtin_amdgcn_s_sleep(8);
        }
        __syncthreads();
        if (t == 0) ST1(base + 160, 1u);               // release flag, own line
    } else {
        if (t == 0) {
            while (LD1(base + 160) == 0u)
                __builtin_amdgcn_s_sleep(8);
        }
        __syncthreads();
    }
    asm volatile("" ::: "memory");
    __syncthreads();
}

// entry tap loads for one key stage (2 samples/wave; sample = blk*4+wv+rep*512)
__device__ __forceinline__ void key_prefetch(const float* __restrict__ in,
                                             int mul, int dbl, int blk,
                                             int lane, int wv,
                                             float xa[2], float xb[2]) {
#pragma unroll
    for (int rep = 0; rep < 2; ++rep) {
        int s = blk * 4 + wv + rep * 512;
        int ii = s >> 5, jj = s & 31;
        int qy = (ii * mul) >> 5, qx = (jj * mul) >> 5;
        int by = dbl ? 2 * qy : qy - 1;
        int bx = dbl ? 2 * qx : qx - 1;
        {
            int l = lane;                    // < 64 < 75: always a valid tap
            int ci = l / 25, rm = l % 25, r = rm / 5, cc = rm % 5;
            int y = by + r, x = bx + cc;
            xa[rep] = ((unsigned)y < 1024u && (unsigned)x < 1024u)
                      ? 2.0f * in[ci * 1048576 + y * 1024 + x] - 1.0f : 0.f;
        }
        xb[rep] = 0.f;
        if (lane < 11) {
            int l = lane + 64;
            int ci = l / 25, rm = l % 25, r = rm / 5, cc = rm % 5;
            int y = by + r, x = bx + cc;
            xb[rep] = ((unsigned)y < 1024u && (unsigned)x < 1024u)
                      ? 2.0f * in[ci * 1048576 + y * 1024 + x] - 1.0f : 0.f;
        }
    }
}

// key values from prefetched taps -> skv LDS (24 floats: [c*8 + rep*4 + wv])
__device__ __forceinline__ void key_stage(const float* __restrict__ sw,
                                          const float* __restrict__ sb,
                                          const float xa[2], const float xb[2],
                                          float* __restrict__ skv,
                                          int lane, int wv) {
#pragma unroll
    for (int rep = 0; rep < 2; ++rep) {
        float p0 = xa[rep] * sw[lane];
        float p1 = xa[rep] * sw[75 + lane];
        float p2 = xa[rep] * sw[150 + lane];
        if (lane < 11) {
            p0 += xb[rep] * sw[64 + lane];
            p1 += xb[rep] * sw[139 + lane];
            p2 += xb[rep] * sw[214 + lane];
        }
#pragma unroll
        for (int off = 32; off > 0; off >>= 1) {
            p0 += __shfl_xor(p0, off, 64);
            p1 += __shfl_xor(p1, off, 64);
            p2 += __shfl_xor(p2, off, 64);
        }
        if (lane == 0) {
            skv[0 * 8 + rep * 4 + wv] = sigmoidf_(p0 + sb[0]);
            skv[1 * 8 + rep * 4 + wv] = sigmoidf_(p1 + sb[1]);
            skv[2 * 8 + rep * 4 + wv] = sigmoidf_(p2 + sb[2]);
        }
    }
}

// softmax over slog[0..99] (LDS) -> satt (LDS); runs in every block
__device__ __forceinline__ void softmax_lds(const float* __restrict__ slog,
                                            float* __restrict__ satt,
                                            int lane, int wv) {
    if (wv == 0) {
        float v1 = slog[lane];
        float v2 = (lane + 64 < 100) ? slog[lane + 64] : -3.4e38f;
        float mx = fmaxf(v1, v2);
#pragma unroll
        for (int off = 32; off > 0; off >>= 1) mx = fmaxf(mx, __shfl_xor(mx, off, 64));
        float e1 = expf(v1 - mx);
        float e2 = (lane + 64 < 100) ? expf(v2 - mx) : 0.f;
        float s = e1 + e2;
#pragma unroll
        for (int off = 32; off > 0; off >>= 1) s += __shfl_xor(s, off, 64);
        float inv = 1.0f / s;
        satt[lane] = e1 * inv;
        if (lane + 64 < 100) satt[lane + 64] = e2 * inv;
    }
    __syncthreads();
}

__global__ __launch_bounds__(256, 1) void k_fused(
    const float* __restrict__ in, const float* __restrict__ cw,
    const float* __restrict__ cb, const float* __restrict__ keys,
    const float* __restrict__ vals, float* __restrict__ out,
    float* __restrict__ ws, unsigned* __restrict__ ctr)
{
    __shared__ float smem[11380];
    float* sk1  = smem;          // 225  kern1 (persists C'->F')
    float* sk2  = smem + 232;    // 225  kern2
    float* satt = smem + 464;    // 100  softmax
    float* sw   = smem + 568;    // 225  conv weights, then w_eff
    float* sb   = smem + 800;    // 3    bias
    float* sW   = smem + 808;    // 1521 composite W [(ci*3+o)*169 + e*13+f]
    float* sWy  = smem + 2332;   // 117
    float* sWx  = smem + 2452;   // 117
    float* sWxy = smem + 2572;   // 9
    float* skv  = smem + 2584;   // 24   block's key samples [c*8+rep*4+wv]
    float* slog = smem + 2608;   // 128  reduced logits
    float* skc  = smem + 2736;   // 2500 keys cols [t*25 + c*8+r*4+w], pad 25
    float* sgx  = smem + 5236;   // 6144 G taps [((ch*4+k)*4+l)*128 + j]

    float* plog1 = ws;           // [128 blocks][128 stride], 100 used
    float* plog2 = ws + 16384;

    const int t = threadIdx.x, lane = t & 63, wv = t >> 6;
    const int blk = blockIdx.x;

    // ---- entry prefetch: key-stage taps (only xa2/xb2 live across bar1) ----
    float xa1[2], xb1[2], xa2[2], xb2[2];
    key_prefetch(in, 510, 1, blk, lane, wv, xa1, xb1);
    key_prefetch(in, 1022, 0, blk, lane, wv, xa2, xb2);

    // ---- entry: keys columns for this block's 8 samples -> LDS (R14 fix) ----
    if (t < 100) {
        const float* kr = keys + t * 3072 + blk * 4;
#pragma unroll
        for (int c = 0; c < 3; ++c)
#pragma unroll
            for (int r = 0; r < 2; ++r) {
                float4 kk = *reinterpret_cast<const float4*>(kr + c * 1024 + r * 512);
                int o = t * 25 + c * 8 + r * 4;
                skc[o]     = kk.x;
                skc[o + 1] = kk.y;
                skc[o + 2] = kk.z;
                skc[o + 3] = kk.w;
            }
    }

    // ---- entry: stage G taps into LDS (registers die here; R14 lesson) ----
    const int j = t & 127, h = t >> 7;
    const int R = (blk * 4093) >> 7;
    const int C = (j * 4093) >> 7;
    const int ybase = (R + 6) >> 2, r0 = (R + 6) & 3, nk = (r0 == 0) ? 4 : 3;
    const int xbase = (C + 6) >> 2, f0 = (C + 6) & 3, nl = (f0 == 0) ? 4 : 3;
#pragma unroll
    for (int k = 0; k < 4; ++k) {
        int iy = ybase - k;
#pragma unroll
        for (int lh = 0; lh < 2; ++lh) {
            int l = h * 2 + lh;
            int ix = xbase - l;
            bool ok = ((unsigned)iy < 1024u) && ((unsigned)ix < 1024u)
                      && (k < nk) && (l < nl);
            int off = iy * 1024 + ix;
            float v0 = ok ? 2.0f * in[off] - 1.0f : 0.f;
            float v1 = ok ? 2.0f * in[1048576 + off] - 1.0f : 0.f;
            float v2 = ok ? 2.0f * in[2097152 + off] - 1.0f : 0.f;
            int si = (k * 4 + l) * 128 + j;
            sgx[si]        = v0;
            sgx[2048 + si] = v1;
            sgx[4096 + si] = v2;
        }
    }

    if (t < 225) sw[t] = cw[t];
    if (t < 3)   sb[t] = cb[t];
    __syncthreads();

    // ---- A: key1 samples -> skv, partial logits -> plog1 (all blocks) ----
    key_stage(sw, sb, xa1, xb1, skv, lane, wv);
    __syncthreads();
    if (t < 100) {
        float s = 0.f;
        const float* kc = skc + t * 25;
#pragma unroll
        for (int i = 0; i < 24; ++i) s += kc[i] * skv[i];
        ST1(plog1 + blk * 128 + t, s);
    }
    gbar(ctr, blk, t);

    // ---- C' (replicated): reduce partials -> softmax -> kern1 -> w_eff ----
    if (t < 100) {
        const float* p = plog1 + t;
        float s0 = 0.f, s1 = 0.f, s2 = 0.f, s3 = 0.f;
#pragma unroll
        for (int b = 0; b < 32; ++b) {
            s0 += LD1(p + (4 * b + 0) * 128);
            s1 += LD1(p + (4 * b + 1) * 128);
            s2 += LD1(p + (4 * b + 2) * 128);
            s3 += LD1(p + (4 * b + 3) * 128);
        }
        slog[t] = (s0 + s1) + (s2 + s3);
    }
    __syncthreads();
    softmax_lds(slog, satt, lane, wv);
    if (t < 225) {
        float s = 0.f;
#pragma unroll
        for (int n = 0; n < 100; ++n) s += vals[n * 225 + t] * satt[n];
        sk1[t] = s;
    }
    __syncthreads();
    if (t < 225) {   // w_eff[co][ci][a][bb] = conv(convT(.,kern1)) composite
        int co = t / 75, rem = t % 75, ci = rem / 25, a = (rem % 25) / 5, bb = rem % 5;
        float s = 0.f;
#pragma unroll
        for (int c = 0; c < 5; ++c) {
            int u = c + 2 * a - 4;
            if ((unsigned)u >= 5u) continue;
#pragma unroll
            for (int d = 0; d < 5; ++d) {
                int v = d + 2 * bb - 4;
                if ((unsigned)v >= 5u) continue;
#pragma unroll
                for (int cm = 0; cm < 3; ++cm)
                    s += sk1[ci * 75 + cm * 25 + c * 5 + d] * cw[co * 75 + cm * 25 + u * 5 + v];
            }
        }
        sw[t] = s;    // nobody reads old sw in this phase
    }
    __syncthreads();

    // ---- D: key2 samples via w_eff -> skv, partials -> plog2 ----
    key_stage(sw, sb, xa2, xb2, skv, lane, wv);
    __syncthreads();
    if (t < 100) {
        float s = 0.f;
        const float* kc = skc + t * 25;
#pragma unroll
        for (int i = 0; i < 24; ++i) s += kc[i] * skv[i];
        ST1(plog2 + blk * 128 + t, s);
    }
    gbar(ctr + 256, blk, t);

    // ---- F' (replicated): reduce -> softmax -> kern2 -> composite tables ----
    if (t < 100) {
        const float* p = plog2 + t;
        float s0 = 0.f, s1 = 0.f, s2 = 0.f, s3 = 0.f;
#pragma unroll
        for (int b = 0; b < 32; ++b) {
            s0 += LD1(p + (4 * b + 0) * 128);
            s1 += LD1(p + (4 * b + 1) * 128);
            s2 += LD1(p + (4 * b + 2) * 128);
            s3 += LD1(p + (4 * b + 3) * 128);
        }
        slog[t] = (s0 + s1) + (s2 + s3);
    }
    __syncthreads();
    softmax_lds(slog, satt, lane, wv);
    if (t < 225) {
        float s = 0.f;
#pragma unroll
        for (int n = 0; n < 100; ++n) s += vals[n * 225 + t] * satt[n];
        sk2[t] = s;
    }
    __syncthreads();
    for (int idx = t; idx < 1521; idx += 256) {   // W
        int ci = idx / 507, rem = idx % 507, o = rem / 169;
        int ef = rem % 169, e = ef / 13, f = ef % 13;
        float s = 0.f;
#pragma unroll
        for (int c = 0; c < 5; ++c) {
            int a = e - 2 * c;
            if ((unsigned)a >= 5u) continue;
#pragma unroll
            for (int d = 0; d < 5; ++d) {
                int b2 = f - 2 * d;
                if ((unsigned)b2 >= 5u) continue;
#pragma unroll
                for (int cm = 0; cm < 3; ++cm)
                    s += sk1[ci * 75 + cm * 25 + c * 5 + d] * sk2[cm * 75 + o * 25 + a * 5 + b2];
            }
        }
        sW[idx] = s;
    }
    if (t < 117) {   // Wy: phantom out1-row (c=1 -> oy1=-1), a=4
        int ci = t / 39, o = (t % 39) / 13, f = t % 13;
        float s = 0.f;
#pragma unroll
        for (int d = 0; d < 5; ++d) {
            int b2 = f - 2 * d;
            if ((unsigned)b2 >= 5u) continue;
#pragma unroll
            for (int cm = 0; cm < 3; ++cm)
                s += sk1[ci * 75 + cm * 25 + 5 + d] * sk2[cm * 75 + o * 25 + 20 + b2];
        }
        sWy[(ci * 3 + o) * 13 + f] = s;
    }
    if (t >= 128 && t < 245) {   // Wx: phantom out1-col (d=1 -> ox1=-1), b=4
        int q = t - 128;
        int ci = q / 39, o = (q % 39) / 13, e = q % 13;
        float s = 0.f;
#pragma unroll
        for (int c = 0; c < 5; ++c) {
            int a = e - 2 * c;
            if ((unsigned)a >= 5u) continue;
#pragma unroll
            for (int cm = 0; cm < 3; ++cm)
                s += sk1[ci * 75 + cm * 25 + c * 5 + 1] * sk2[cm * 75 + o * 25 + a * 5 + 4];
        }
        sWx[(ci * 3 + o) * 13 + e] = s;
    }
    if (t >= 246 && t < 255) {   // Wxy overlap
        int q = t - 246;
        int ci = q / 3, o = q % 3;
        float s = 0.f;
#pragma unroll
        for (int cm = 0; cm < 3; ++cm)
            s += sk1[ci * 75 + cm * 25 + 5 + 1] * sk2[cm * 75 + o * 25 + 20 + 4];
        sWxy[ci * 3 + o] = s;
    }
    __syncthreads();

    // ---- G: final sampled composite convT + sigmoid (taps + tables in LDS) ----
    if (t < 128) {
        float a0 = 0.f, a1 = 0.f, a2 = 0.f;
#pragma unroll
        for (int k = 0; k < 4; ++k) {
            if (k < nk) {
                int e = r0 + 4 * k;
#pragma unroll
                for (int l = 0; l < 4; ++l) {
                    if (l < nl) {
                        int f = f0 + 4 * l;
                        int wi = e * 13 + f;
                        int si = (k * 4 + l) * 128 + j;
                        float x0 = sgx[si], x1 = sgx[2048 + si], x2 = sgx[4096 + si];
                        a0 += x0 * sW[wi]       + x1 * sW[507 + wi]  + x2 * sW[1014 + wi];
                        a1 += x0 * sW[169 + wi] + x1 * sW[676 + wi]  + x2 * sW[1183 + wi];
                        a2 += x0 * sW[338 + wi] + x1 * sW[845 + wi]  + x2 * sW[1352 + wi];
                    }
                }
            }
        }
        if (R == 0) {
            for (int l = 0; l < nl; ++l) {
                int ix = xbase - l;
                if ((unsigned)ix >= 1024u) continue;
                int f = f0 + 4 * l;
                float x0 = 2.0f * in[ix] - 1.0f;
                float x1 = 2.0f * in[1048576 + ix] - 1.0f;
                float x2 = 2.0f * in[2097152 + ix] - 1.0f;
                a0 -= x0 * sWy[f]      + x1 * sWy[39 + f] + x2 * sWy[78 + f];
                a1 -= x0 * sWy[13 + f] + x1 * sWy[52 + f] + x2 * sWy[91 + f];
                a2 -= x0 * sWy[26 + f] + x1 * sWy[65 + f] + x2 * sWy[104 + f];
            }
        }
        if (C == 0) {
            for (int k = 0; k < nk; ++k) {
                int iy = ybase - k;
                if ((unsigned)iy >= 1024u) continue;
                int e = r0 + 4 * k;
                int off = iy * 1024;
                float x0 = 2.0f * in[off] - 1.0f;
                float x1 = 2.0f * in[1048576 + off] - 1.0f;
                float x2 = 2.0f * in[2097152 + off] - 1.0f;
                a0 -= x0 * sWx[e]      + x1 * sWx[39 + e] + x2 * sWx[78 + e];
                a1 -= x0 * sWx[13 + e] + x1 * sWx[52 + e] + x2 * sWx[91 + e];
                a2 -= x0 * sWx[26 + e] + x1 * sWx[65 + e] + x2 * sWx[104 + e];
            }
        }
        if (R == 0 && C == 0) {
            float x0 = 2.0f * in[0] - 1.0f;
            float x1 = 2.0f * in[1048576] - 1.0f;
            float x2 = 2.0f * in[2097152] - 1.0f;
            a0 += x0 * sWxy[0] + x1 * sWxy[3] + x2 * sWxy[6];
            a1 += x0 * sWxy[1] + x1 * sWxy[4] + x2 * sWxy[7];
            a2 += x0 * sWxy[2] + x1 * sWxy[5] + x2 * sWxy[8];
        }
        int T = blk * 128 + j;
        out[T]             = sigmoidf_(a0);
        out[16384 + T]     = sigmoidf_(a1);
        out[2 * 16384 + T] = sigmoidf_(a2);
    }
}

extern "C" void kernel_launch(void* const* d_in, const int* in_sizes, int n_in,
                              void* d_out, int out_size, void* d_ws, size_t ws_size,
                              hipStream_t stream) {
    const float* in   = (const float*)d_in[0];   // [3,1024,1024]
    const float* cw   = (const float*)d_in[1];   // [3,3,5,5]
    const float* cb   = (const float*)d_in[2];   // [3]
    const float* keys = (const float*)d_in[3];   // [100,3072]
    const float* vals = (const float*)d_in[4];   // [100,225]
    float* out = (float*)d_out;                  // [3,128,128] fp32

    unsigned* ctr = (unsigned*)d_ws;             // 2 barriers x 1KB (store-based)
    float* wsf = (float*)((char*)d_ws + 8192);   // float scratch: 2 x 16384 plog

    hipMemsetAsync(d_ws, 0, 2048, stream);       // zero barrier state
    k_fused<<<GRID, 256, 0, stream>>>(in, cw, cb, keys, vals, out, wsf, ctr);
}